// Round 4
// baseline (96.982 us; speedup 1.0000x reference)
//
#include <hip/hip_runtime.h>

// Involution (RedNet-style), N=4 C=256 H=W=56, K=7, G=16, ratio=4 (Cr=64).
// k1: t[o][px] = relu(BN(x·w1^T + b1)), c-split across 4 waves + LDS reduce.
// k2: fused kernel-gen as OUTER PRODUCT over o (1 live t value per lane,
//     ker[13] accumulators per wave) + involution gather + 4-wave reduce.

namespace {
constexpr int Nn  = 4;
constexpr int Cc  = 256;
constexpr int Hh  = 56;
constexpr int Ww  = 56;
constexpr int HW  = Hh * Ww;        // 3136
constexpr int NPX = Nn * HW;        // 12544
constexpr int KK  = 49;             // 7x7
constexpr int Cr  = 64;             // reduced channels
}

// ---------------------------------------------------------------------------
// Kernel 1: 1x1 conv + BatchNorm(inference) + ReLU
// grid (196, 8) x 256. lane = pixel; wave wv covers c in [wv*64, wv*64+64);
// block computes 8 output channels o = blockIdx.y*8 .. +8 via LDS reduction.
// 1568 blocks = 6272 waves (~6/SIMD). 64 loads + 512 FMA per lane.
// t layout: [64][12544]  (coalesced stores here, coalesced loads in k2)
// ---------------------------------------------------------------------------
extern "C" __global__ void __launch_bounds__(256, 8)
k1_conv_bn_relu(const float* __restrict__ x,  const float* __restrict__ w1,
                const float* __restrict__ b1, const float* __restrict__ gamma,
                const float* __restrict__ beta, const float* __restrict__ mean,
                const float* __restrict__ var,  float* __restrict__ t)
{
    __shared__ float red[4][8][64];                          // 8 KB

    const int lane = threadIdx.x & 63;
    const int wv   = __builtin_amdgcn_readfirstlane(threadIdx.x >> 6);  // 0..3
    const int px   = blockIdx.x * 64 + lane;                 // exact: 196*64=12544
    const int o0   = __builtin_amdgcn_readfirstlane((int)blockIdx.y * 8);

    const int n  = px / HW;
    const int hw = px - n * HW;
    const float* xb = x + (size_t)n * Cc * HW + hw;
    const int c0 = wv * 64;

    float acc[8];
#pragma unroll
    for (int i = 0; i < 8; ++i) acc[i] = 0.f;

#pragma unroll 8
    for (int cc = 0; cc < 64; ++cc) {
        const int c = c0 + cc;
        const float xv = xb[(size_t)c * HW];                 // coalesced across lanes
#pragma unroll
        for (int oo = 0; oo < 8; ++oo)
            acc[oo] = fmaf(xv, w1[(o0 + oo) * Cc + c], acc[oo]);  // uniform -> s_load
    }

#pragma unroll
    for (int oo = 0; oo < 8; ++oo) red[wv][oo][lane] = acc[oo];
    __syncthreads();

    // each wave finalizes 2 output channels
#pragma unroll
    for (int j = 0; j < 2; ++j) {
        const int oo = wv * 2 + j;
        const int o  = o0 + oo;
        const float s = red[0][oo][lane] + red[1][oo][lane]
                      + red[2][oo][lane] + red[3][oo][lane];
        const float inv = rsqrtf(var[o] + 1e-5f);
        const float sc  = gamma[o] * inv;
        const float sh  = fmaf(b1[o] - mean[o], sc, beta[o]);
        const float v   = fmaf(s, sc, sh);
        t[(size_t)o * NPX + px] = v > 0.f ? v : 0.f;         // coalesced store
    }
}

// ---------------------------------------------------------------------------
// Kernel 2: fused kernel-generation (outer-product over o) + involution.
// grid (224 nh, 16 g) x 256. block = (n,h) row & group g; lane = pixel w.
// Wave wv owns taps k = wv + 4j (j=0..12; k>=49 masked). Phase A accumulates
// ker[j] = b2[k] + sum_o t[o,px]*w2[k,o] with ONE t value live at a time
// (w2 rows are wave-uniform -> scalar loads). Phase B gathers x. Phase C
// reduces acc[16] across the 4 waves via LDS.
// 3584 blocks = 14336 waves (~14/SIMD queued); ~55-70 VGPR -> deep occupancy.
// ---------------------------------------------------------------------------
extern "C" __global__ void __launch_bounds__(256, 4)
k2_involution(const float* __restrict__ x,  const float* __restrict__ t,
              const float* __restrict__ w2, const float* __restrict__ b2,
              float* __restrict__ out)
{
    __shared__ float red[4][16][64];                         // 16 KB

    const int lane = threadIdx.x & 63;                       // pixel w (0..55 active)
    const int wv   = __builtin_amdgcn_readfirstlane(threadIdx.x >> 6);  // 0..3
    const int nh   = blockIdx.x;                             // n*56 + h
    const int n    = nh / Hh;
    const int h    = nh - n * Hh;
    const int g    = __builtin_amdgcn_readfirstlane((int)blockIdx.y);
    const int wcl  = lane < Ww ? lane : (Ww - 1);            // clamp for safe t loads
    const int pxb  = nh * Ww;                                // n*3136 + h*56

    const float* tp  = t  + pxb + wcl;
    const float* w2g = w2 + g * KK * Cr;
    const float* b2g = b2 + g * KK;

    // ---- Phase A: ker[j] for taps k = wv + 4j (outer product over o) ----
    float ker[13];
#pragma unroll
    for (int j = 0; j < 13; ++j) {
        int k = wv + 4 * j; if (k > KK - 1) k = KK - 1;      // clamp (junk discarded)
        ker[j] = b2g[k];
    }

#pragma unroll 2
    for (int o = 0; o < Cr; o += 4) {                        // 16 iterations
        const float tv0 = tp[(size_t)(o + 0) * NPX];         // coalesced across lanes
        const float tv1 = tp[(size_t)(o + 1) * NPX];
        const float tv2 = tp[(size_t)(o + 2) * NPX];
        const float tv3 = tp[(size_t)(o + 3) * NPX];
#pragma unroll
        for (int j = 0; j < 13; ++j) {
            int k = wv + 4 * j; if (k > KK - 1) k = KK - 1;
            const float* wr = w2g + k * Cr + o;              // wave-uniform -> s_load
            float kj = ker[j];
            kj = fmaf(tv0, wr[0], kj);
            kj = fmaf(tv1, wr[1], kj);
            kj = fmaf(tv2, wr[2], kj);
            kj = fmaf(tv3, wr[3], kj);
            ker[j] = kj;
        }
    }

    // ---- Phase B: involution gather ----
    float acc[16];
#pragma unroll
    for (int i = 0; i < 16; ++i) acc[i] = 0.f;

    const float* xg = x + (size_t)n * Cc * HW + (size_t)(g * 16) * HW;

#pragma unroll
    for (int j = 0; j < 13; ++j) {
        const int k = wv + 4 * j;
        if (k >= KK) break;                                  // uniform (waves 1..3, j=12)
        const int kh = k / 7;
        const int kw = k - kh * 7;
        const int hh = h + kh - 3;
        if (hh < 0 || hh >= Hh) continue;                    // wave-uniform skip
        const int ww = lane + kw - 3;
        const float kerv = ker[j];
        const float* xr = xg + hh * Ww + ww;
        if (ww >= 0 && ww < Ww) {                            // per-lane mask
#pragma unroll
            for (int c = 0; c < 16; ++c)
                acc[c] = fmaf(xr[(size_t)c * HW], kerv, acc[c]);
        }
    }

    // ---- Phase C: cross-wave reduction ----
#pragma unroll
    for (int c = 0; c < 16; ++c)
        red[wv][c][lane] = acc[c];
    __syncthreads();

    if (lane < Ww) {
        float* og = out + (size_t)n * Cc * HW + (size_t)(g * 16) * HW + h * Ww + lane;
#pragma unroll
        for (int j = 0; j < 4; ++j) {
            const int c = wv * 4 + j;
            const float s = red[0][c][lane] + red[1][c][lane]
                          + red[2][c][lane] + red[3][c][lane];
            og[c * HW] = s;                                  // coalesced per c
        }
    }
}

// ---------------------------------------------------------------------------
extern "C" void kernel_launch(void* const* d_in, const int* in_sizes, int n_in,
                              void* d_out, int out_size, void* d_ws, size_t ws_size,
                              hipStream_t stream)
{
    const float* x     = (const float*)d_in[0];
    const float* w1    = (const float*)d_in[1];
    const float* b1    = (const float*)d_in[2];
    const float* gamma = (const float*)d_in[3];
    const float* beta  = (const float*)d_in[4];
    const float* mean  = (const float*)d_in[5];
    const float* var   = (const float*)d_in[6];
    const float* w2    = (const float*)d_in[7];
    const float* b2    = (const float*)d_in[8];

    float* t   = (float*)d_ws;        // 64 * 12544 floats = 3.2 MB scratch
    float* out = (float*)d_out;

    k1_conv_bn_relu<<<dim3(NPX / 64, 8), 256, 0, stream>>>(
        x, w1, b1, gamma, beta, mean, var, t);
    k2_involution<<<dim3(Nn * Hh, 16), 256, 0, stream>>>(
        x, t, w2, b2, out);
}